// Round 9
// baseline (197.487 us; speedup 1.0000x reference)
//
#include <hip/hip_runtime.h>
#include <math.h>

#define N_    32
#define CIN   128
#define H_    56
#define W_    56
#define COUT  256
#define OH    28
#define OW    28
#define M_    (N_ * OH * OW)      // 25088
#define OUTSZ (M_ * COUT)         // 6,422,528
#define EPS_  0.007f

typedef unsigned short U16;
typedef float f32x4  __attribute__((ext_vector_type(4)));
typedef short bf16x8 __attribute__((ext_vector_type(8)));

// ws float-region layout
#define SCALE_IDX 0
#define ZERO_IDX  8             // wsf[8..15]: 32B zero page for OOB global_load_lds
#define WSQ_IDX   16            // 256 floats
#define PSQ_IDX   512           // 25088 floats
#define U16_BYTE_OFF 102400     // = 25600 floats, 256B aligned

__device__ __forceinline__ U16 f2bf(float f) {
    unsigned int u = __builtin_bit_cast(unsigned int, f);
    u = (u + 0x7fffu + ((u >> 16) & 1u)) >> 16;   // RNE
    return (U16)u;
}
__device__ __forceinline__ float b2f(U16 h) {
    unsigned int u = ((unsigned int)h) << 16;
    return __builtin_bit_cast(float, u);
}

__device__ __forceinline__ void gl_lds16(const U16* g, U16* l) {
    __builtin_amdgcn_global_load_lds((const __attribute__((address_space(1))) void*)g,
                                     (__attribute__((address_space(3))) void*)l, 16, 0, 0);
}
__device__ __forceinline__ unsigned lds_addr(const U16* p) {
    return (unsigned)(size_t)(const __attribute__((address_space(3))) U16*)p;
}

// ---------------- fused prep: x transpose + weight reorder + wsq/scale/zero ----------------
__global__ void k_prep(const float* __restrict__ x,
                       const float* __restrict__ w_yat,
                       const float* __restrict__ w_lin,
                       const float* __restrict__ w_short,
                       const float* __restrict__ alpha,
                       U16* __restrict__ xt, U16* __restrict__ B1,
                       U16* __restrict__ B3, U16* __restrict__ B2,
                       float* __restrict__ wsf) {
    int b = blockIdx.x, t = threadIdx.x;
    if (b < 6272) {
        int idx = b * 256 + t;                     // 1,605,632 exactly
        int ci8 = idx & 15;
        int px  = idx >> 4;                        // n*3136 + hw
        int n   = px / 3136;
        int hw  = px - n * 3136;
        const float* src = x + ((size_t)n * 128 + ci8 * 8) * 3136 + hw;
        unsigned int o[4];
#pragma unroll
        for (int j = 0; j < 4; ++j) {
            float a = src[(size_t)(2 * j)     * 3136];
            float c = src[(size_t)(2 * j + 1) * 3136];
            o[j] = (unsigned)f2bf(a) | ((unsigned)f2bf(c) << 16);
        }
        *(uint4*)&xt[(size_t)px * 128 + ci8 * 8] = *(const uint4*)o;
    } else if (b < 9856) {
        int idx = (b - 6272) * 256 + t;            // 917,504 exactly
        if (idx < 294912) {
            int co = idx / 1152, k = idx % 1152;
            int khkw = k >> 7, ci = k & 127;
            B1[idx] = f2bf(w_yat[(co * 128 + ci) * 9 + khkw]);
        } else if (idx < 294912 + 589824) {
            int i2 = idx - 294912;
            int co = i2 / 2304, k = i2 % 2304;
            int khkw = k >> 8, cy = k & 255;
            B3[i2] = f2bf(w_lin[(co * 256 + cy) * 9 + khkw]);
        } else {
            int i3 = idx - (294912 + 589824);      // < 32768
            B2[i3] = f2bf(w_short[i3]);
        }
    } else {
        int co = b - 9856, lane = t & 63, wv = t >> 6;
        const float* wc = w_yat + (size_t)co * 1152;
        float s = 0.f;
        for (int i = t; i < 1152; i += 256) { float v = wc[i]; s += v * v; }
#pragma unroll
        for (int off = 32; off >= 1; off >>= 1) s += __shfl_xor(s, off);
        __shared__ float red[4];
        if (lane == 0) red[wv] = s;
        __syncthreads();
        if (t == 0) {
            wsf[WSQ_IDX + co] = red[0] + red[1] + red[2] + red[3];
            if (co == 0) wsf[SCALE_IDX] = powf(16.0f / log1pf(256.0f), alpha[0]);
        }
        if (co == 0 && t >= 8 && t < 16) wsf[ZERO_IDX + (t - 8)] = 0.f;
    }
}

// ---------------- per-patch squared norm: one wave per output pixel ----------------
__global__ void k_psq(const U16* __restrict__ xt, float* __restrict__ wsf) {
    int t = threadIdx.x, lane = t & 63, wv = t >> 6;
    int gm = blockIdx.x * 4 + wv;                  // < 25088 exactly
    int ow = gm % 28, tt = gm / 28;
    int oh = tt % 28, n = tt / 28;
    const U16* xb = xt + (size_t)n * 56 * 56 * 128;
    float s = 0.f;
#pragma unroll
    for (int kh = 0; kh < 3; ++kh) {
        int ih = oh * 2 - 1 + kh;
        if ((unsigned)ih >= 56) continue;
#pragma unroll
        for (int kw = 0; kw < 3; ++kw) {
            int iw = ow * 2 - 1 + kw;
            if ((unsigned)iw >= 56) continue;
            unsigned int v = *(const unsigned int*)&xb[(size_t)((ih * 56 + iw) << 7) + lane * 2];
            float f0 = b2f((U16)(v & 0xffff)), f1 = b2f((U16)(v >> 16));
            s += f0 * f0 + f1 * f1;
        }
    }
#pragma unroll
    for (int off = 32; off >= 1; off >>= 1) s += __shfl_xor(s, off);
    if (lane == 0) wsf[PSQ_IDX + gm] = s;
}

// ---------------- MFMA implicit-GEMM, BM=128 BN=64 BK=64 ----------------
// T3+T4 pipeline: static dbuf, raw s_barrier + counted s_waitcnt vmcnt(6) (never 0
// mid-loop), asm ds_read_b128 (opaque to compiler hazard pass), T5 setprio on MFMA.
// Per tile t: vmcnt(6) -> barrier -> ds_read+MFMA -> barrier -> STAGE(t+2).
// MODE 0: yat dot conv (3x3 s2 p1 over xt) -> ybuf bf16; fused 1x1 s2 shortcut -> out
// MODE 3: lin 3x3 s1 p1 over ybuf, split-K=2 (bid>=784 -> K-half 1), bf16 partials
template<int KTOT, int MODE>
__launch_bounds__(256, 3)
__global__ void k_gemm(const U16* __restrict__ Asrc, const U16* __restrict__ Bp,
                       const U16* __restrict__ B2p,
                       const float* __restrict__ wsf, U16* __restrict__ ybuf,
                       float* __restrict__ out) {
    __shared__ U16 A0s[128 * 64];                  // 16 KB
    __shared__ U16 A1s[128 * 64];                  // 16 KB
    __shared__ U16 B0s[64 * 64];                   // 8 KB
    __shared__ U16 B1s[64 * 64];                   // 8 KB
    __shared__ float psq_s[128];
    __shared__ float wsq_s[64];

    int t = threadIdx.x, lane = t & 63, wv = t >> 6;
    int wr = wv >> 1, wc = wv & 1;                 // wave tile: rows wr*64 (4 frags), cols wc*32 (2 frags)
    int bid = blockIdx.x;
    int s = 0, inner = bid;
    if (MODE == 3) { s = (bid >= 784) ? 1 : 0; inner = bid - 784 * s; }
    int logical = (inner & 7) * 98 + (inner >> 3); // XCD swizzle (784 = 8*98, bijective)
    int m0 = (logical >> 2) * 128;
    int co_base = (logical & 3) * 64;

    if (MODE == 0) {
        if (t < 128)       psq_s[t] = wsf[PSQ_IDX + m0 + t];
        else if (t < 192)  wsq_s[t - 128] = wsf[WSQ_IDX + co_base + (t - 128)];
    }

    const U16* zptr = (const U16*)&wsf[ZERO_IDX];

    // A-staging coords: thread t stages rows r0+32*rr (rr=0..3), 16B each; LDS dest linear
    int r0 = t >> 3, phys = t & 7;
    int aplog = phys ^ (r0 & 7);
    int an[4], aoh[4], aow[4];
#pragma unroll
    for (int rr = 0; rr < 4; ++rr) {
        int am = m0 + r0 + 32 * rr;
        int tt = am / 28; aow[rr] = am - tt * 28; an[rr] = tt / 28; aoh[rr] = tt - an[rr] * 28;
    }

    // B-staging: thread t stages cols bcol, bcol+32
    int bcol = t >> 3;
    int bplog = phys ^ (bcol & 7);
    const U16* bbase = Bp + (size_t)(co_base + bcol) * KTOT + bplog * 8;

    f32x4 acc[4][2] = {};
    f32x4 acc2[4][2] = {};                         // identity (MODE0 only; DCE'd in MODE3)

    // ---- B2 shortcut fragments: preload to regs pre-loop, pin live (32-bit components) ----
    uint4 b2r[8] = {};
    if (MODE == 0) {
#pragma unroll
        for (int tsel = 0; tsel < 2; ++tsel)
#pragma unroll
            for (int kk = 0; kk < 2; ++kk)
#pragma unroll
                for (int j = 0; j < 2; ++j) {
                    int col = wc * 32 + j * 16 + (lane & 15);
                    int q = kk * 4 + (lane >> 4);
                    b2r[tsel * 4 + kk * 2 + j] =
                        *(const uint4*)&B2p[(size_t)(co_base + col) * 128 + tsel * 64 + q * 8];
                }
#pragma unroll
        for (int i = 0; i < 8; ++i)
            asm volatile("" :: "v"(b2r[i].x), "v"(b2r[i].y), "v"(b2r[i].z), "v"(b2r[i].w));
    }

    int ks0 = (MODE == 3) ? s * 18 : 0;            // 18 K-tiles of 64 in both modes

    auto stage = [&](int ks, U16 (&Ab)[128 * 64], U16 (&Bb)[64 * 64]) {
        int k0 = ks * 64;
        if (MODE == 0) {
            int khkw = k0 >> 7, ci0 = k0 & 127;
            int kh = khkw / 3, kw = khkw - 3 * kh;
#pragma unroll
            for (int rr = 0; rr < 4; ++rr) {
                int ih = aoh[rr] * 2 - 1 + kh, iw = aow[rr] * 2 - 1 + kw;
                bool v = ((unsigned)ih < 56) & ((unsigned)iw < 56);
                const U16* sp = v ? Asrc + ((size_t)((an[rr] * 56 + ih) * 56 + iw) << 7) + ci0 + aplog * 8 : zptr;
                gl_lds16(sp, &Ab[(size_t)(rr * 256 + t) * 8]);
            }
        } else {
            int khkw = k0 >> 8, cy0 = k0 & 255;
            int kh = khkw / 3, kw = khkw - 3 * kh;
#pragma unroll
            for (int rr = 0; rr < 4; ++rr) {
                int ih = aoh[rr] - 1 + kh, iw = aow[rr] - 1 + kw;
                bool v = ((unsigned)ih < 28) & ((unsigned)iw < 28);
                const U16* sp = v ? Asrc + ((size_t)((an[rr] * 28 + ih) * 28 + iw) << 8) + cy0 + aplog * 8 : zptr;
                gl_lds16(sp, &Ab[(size_t)(rr * 256 + t) * 8]);
            }
        }
#pragma unroll
        for (int r = 0; r < 2; ++r)
            gl_lds16(bbase + (size_t)r * 32 * KTOT + k0, &Bb[(size_t)(r * 256 + t) * 8]);
    };

    auto compute = [&](int tl, const U16 (&Ab)[128 * 64], const U16 (&Bb)[64 * 64]) {
#pragma unroll
        for (int kk = 0; kk < 2; ++kk) {
            uint4 au[4], bu[2];
#pragma unroll
            for (int i = 0; i < 4; ++i) {
                int row = wr * 64 + i * 16 + (lane & 15);
                int pp = (kk * 4 + (lane >> 4)) ^ (row & 7);
                unsigned ad = lds_addr(&Ab[(row * 8 + pp) * 8]);
                asm volatile("ds_read_b128 %0, %1" : "=v"(au[i]) : "v"(ad));
            }
#pragma unroll
            for (int j = 0; j < 2; ++j) {
                int col = wc * 32 + j * 16 + (lane & 15);
                int pp = (kk * 4 + (lane >> 4)) ^ (col & 7);
                unsigned bd = lds_addr(&Bb[(col * 8 + pp) * 8]);
                asm volatile("ds_read_b128 %0, %1" : "=v"(bu[j]) : "v"(bd));
            }
            asm volatile("s_waitcnt lgkmcnt(0)" ::: "memory");
            __builtin_amdgcn_sched_barrier(0);
            __builtin_amdgcn_s_setprio(1);
#pragma unroll
            for (int i = 0; i < 4; ++i)
#pragma unroll
                for (int j = 0; j < 2; ++j)
                    acc[i][j] = __builtin_amdgcn_mfma_f32_16x16x32_bf16(
                        __builtin_bit_cast(bf16x8, au[i]), __builtin_bit_cast(bf16x8, bu[j]),
                        acc[i][j], 0, 0, 0);
            if (MODE == 0 && (tl == 8 || tl == 9)) {   // center tap: fused 1x1 shortcut
#pragma unroll
                for (int j = 0; j < 2; ++j) {
                    uint4 bv = (tl == 8) ? b2r[kk * 2 + j] : b2r[4 + kk * 2 + j];
#pragma unroll
                    for (int i = 0; i < 4; ++i)
                        acc2[i][j] = __builtin_amdgcn_mfma_f32_16x16x32_bf16(
                            __builtin_bit_cast(bf16x8, au[i]), __builtin_bit_cast(bf16x8, bv),
                            acc2[i][j], 0, 0, 0);
                }
            }
            __builtin_amdgcn_s_setprio(0);
        }
    };

    // ---- T3+T4 pipeline: 18 tiles, depth-2, counted vmcnt ----
    stage(ks0 + 0, A0s, B0s);
    stage(ks0 + 1, A1s, B1s);
    asm volatile("s_waitcnt vmcnt(6) lgkmcnt(0)" ::: "memory");   // tile0 landed; psq/wsq visible
    __builtin_amdgcn_s_barrier();
    compute(0, A0s, B0s);
    __builtin_amdgcn_s_barrier();
    stage(ks0 + 2, A0s, B0s);

    for (int kq = 1; kq < 17; kq += 2) {
        // odd tile kq in A1/B1
        asm volatile("s_waitcnt vmcnt(6)" ::: "memory");
        __builtin_amdgcn_s_barrier();
        compute(kq, A1s, B1s);
        __builtin_amdgcn_s_barrier();
        if (kq + 2 < 18) stage(ks0 + kq + 2, A1s, B1s);
        // even tile kq+1 in A0/B0
        asm volatile("s_waitcnt vmcnt(6)" ::: "memory");
        __builtin_amdgcn_s_barrier();
        compute(kq + 1, A0s, B0s);
        __builtin_amdgcn_s_barrier();
        if (kq + 3 < 18) stage(ks0 + kq + 3, A0s, B0s);
    }
    // tile 17 (odd): nothing younger in flight -> full drain
    asm volatile("s_waitcnt vmcnt(0)" ::: "memory");
    __builtin_amdgcn_s_barrier();
    compute(17, A1s, B1s);

    // ---- epilogue ----
    float scale = (MODE == 0) ? wsf[SCALE_IDX] : 0.f;
#pragma unroll
    for (int i = 0; i < 4; ++i)
#pragma unroll
        for (int j = 0; j < 2; ++j)
#pragma unroll
            for (int r = 0; r < 4; ++r) {
                int row = wr * 64 + i * 16 + ((lane >> 4) << 2) + r;
                int coll = wc * 32 + j * 16 + (lane & 15);
                float v = acc[i][j][r];
                int m = m0 + row;
                int ow = m % 28, tt2 = m / 28;
                int oh = tt2 % 28, n = tt2 / 28;
                int co = co_base + coll;
                size_t oidx = ((size_t)(n * 256 + co) * 28 + oh) * 28 + ow;
                if (MODE == 0) {
                    float dist = psq_s[row] + wsq_s[coll] - 2.0f * v + EPS_;
                    float y = v * v / dist * scale;
                    ybuf[(size_t)m * 256 + co] = f2bf(y);
                    out[oidx] = acc2[i][j][r];
                } else {
                    ybuf[(size_t)s * OUTSZ + oidx] = f2bf(v);   // ybuf param = partial base (xt region)
                }
            }
}

// ---------------- split-K reduction: out += p0 + p1 (fully coalesced, deterministic) ----------
__global__ void k_red(const U16* __restrict__ p, float* __restrict__ out) {
    int tid = blockIdx.x * 256 + threadIdx.x;      // 802,816 = 3136*256
    size_t base = (size_t)tid * 8;
    uint4 a = *(const uint4*)(p + base);
    uint4 b = *(const uint4*)(p + (size_t)OUTSZ + base);
    float4 o0 = *(float4*)(out + base);
    float4 o1 = *(float4*)(out + base + 4);
    const unsigned* aw = (const unsigned*)&a;
    const unsigned* bw = (const unsigned*)&b;
    float r[8];
#pragma unroll
    for (int w = 0; w < 4; ++w) {
        r[2 * w]     = b2f((U16)(aw[w] & 0xffff)) + b2f((U16)(bw[w] & 0xffff));
        r[2 * w + 1] = b2f((U16)(aw[w] >> 16))    + b2f((U16)(bw[w] >> 16));
    }
    o0.x += r[0]; o0.y += r[1]; o0.z += r[2]; o0.w += r[3];
    o1.x += r[4]; o1.y += r[5]; o1.z += r[6]; o1.w += r[7];
    *(float4*)(out + base)     = o0;
    *(float4*)(out + base + 4) = o1;
}

extern "C" void kernel_launch(void* const* d_in, const int* in_sizes, int n_in,
                              void* d_out, int out_size, void* d_ws, size_t ws_size,
                              hipStream_t stream) {
    const float* x       = (const float*)d_in[0];
    const float* w_yat   = (const float*)d_in[1];
    const float* alpha   = (const float*)d_in[2];
    const float* w_lin   = (const float*)d_in[3];
    const float* w_short = (const float*)d_in[4];
    float* out = (float*)d_out;
    float* wsf = (float*)d_ws;

    U16* xt = (U16*)((char*)d_ws + U16_BYTE_OFF);
    U16* yb = xt + (size_t)N_ * H_ * W_ * CIN;        // 12,845,056 U16
    U16* B1 = yb + (size_t)OUTSZ;                     // +6,422,528
    U16* B2 = B1 + 1152 * COUT;                       // +294,912
    U16* B3 = B2 + CIN * COUT;                        // +32,768   (B3: 589,824)
    // split-K partials alias xt (dead after gemm0): 2 x OUTSZ U16 exactly

    k_prep<<<10112, 256, 0, stream>>>(x, w_yat, w_lin, w_short, alpha, xt, B1, B3, B2, wsf);
    k_psq <<<6272,  256, 0, stream>>>(xt, wsf);

    k_gemm<1152, 0><<<784,  256, 0, stream>>>(xt, B1, B2, wsf, yb, out);
    k_gemm<2304, 3><<<1568, 256, 0, stream>>>(yb, B3, nullptr, wsf, xt, nullptr);
    k_red <<<3136, 256, 0, stream>>>(xt, out);
}

// Round 10
// 145.094 us; speedup vs baseline: 1.3611x; 1.3611x over previous
//
#include <hip/hip_runtime.h>
#include <math.h>

#define N_    32
#define CIN   128
#define H_    56
#define W_    56
#define COUT  256
#define OH    28
#define OW    28
#define M_    (N_ * OH * OW)      // 25088
#define OUTSZ (M_ * COUT)         // 6,422,528
#define EPS_  0.007f

typedef unsigned short U16;
typedef float f32x4  __attribute__((ext_vector_type(4)));
typedef short bf16x8 __attribute__((ext_vector_type(8)));

// ws float-region layout
#define SCALE_IDX 0
#define ZERO_IDX  8             // wsf[8..15]: 32B zero page for OOB global_load_lds
#define WSQ_IDX   16            // 256 floats
#define PSQ_IDX   512           // 25088 floats
#define U16_BYTE_OFF 102400     // = 25600 floats, 256B aligned

__device__ __forceinline__ U16 f2bf(float f) {
    unsigned int u = __builtin_bit_cast(unsigned int, f);
    u = (u + 0x7fffu + ((u >> 16) & 1u)) >> 16;   // RNE
    return (U16)u;
}
__device__ __forceinline__ float b2f(U16 h) {
    unsigned int u = ((unsigned int)h) << 16;
    return __builtin_bit_cast(float, u);
}

__device__ __forceinline__ void gl_lds16(const U16* g, U16* l) {
    __builtin_amdgcn_global_load_lds((const __attribute__((address_space(1))) void*)g,
                                     (__attribute__((address_space(3))) void*)l, 16, 0, 0);
}

// ---------------- fused prep: x transpose + weight reorder + wsq/scale/zero ----------------
__global__ void k_prep(const float* __restrict__ x,
                       const float* __restrict__ w_yat,
                       const float* __restrict__ w_lin,
                       const float* __restrict__ w_short,
                       const float* __restrict__ alpha,
                       U16* __restrict__ xt, U16* __restrict__ B1,
                       U16* __restrict__ B3, U16* __restrict__ B2,
                       float* __restrict__ wsf) {
    int b = blockIdx.x, t = threadIdx.x;
    if (b < 6272) {
        int idx = b * 256 + t;                     // 1,605,632 exactly
        int ci8 = idx & 15;
        int px  = idx >> 4;                        // n*3136 + hw
        int n   = px / 3136;
        int hw  = px - n * 3136;
        const float* src = x + ((size_t)n * 128 + ci8 * 8) * 3136 + hw;
        unsigned int o[4];
#pragma unroll
        for (int j = 0; j < 4; ++j) {
            float a = src[(size_t)(2 * j)     * 3136];
            float c = src[(size_t)(2 * j + 1) * 3136];
            o[j] = (unsigned)f2bf(a) | ((unsigned)f2bf(c) << 16);
        }
        *(uint4*)&xt[(size_t)px * 128 + ci8 * 8] = *(const uint4*)o;
    } else if (b < 9856) {
        int idx = (b - 6272) * 256 + t;            // 917,504 exactly
        if (idx < 294912) {
            int co = idx / 1152, k = idx % 1152;
            int khkw = k >> 7, ci = k & 127;
            B1[idx] = f2bf(w_yat[(co * 128 + ci) * 9 + khkw]);
        } else if (idx < 294912 + 589824) {
            int i2 = idx - 294912;
            int co = i2 / 2304, k = i2 % 2304;
            int khkw = k >> 8, cy = k & 255;
            B3[i2] = f2bf(w_lin[(co * 256 + cy) * 9 + khkw]);
        } else {
            int i3 = idx - (294912 + 589824);      // < 32768
            B2[i3] = f2bf(w_short[i3]);
        }
    } else {
        int co = b - 9856, lane = t & 63, wv = t >> 6;
        const float* wc = w_yat + (size_t)co * 1152;
        float s = 0.f;
        for (int i = t; i < 1152; i += 256) { float v = wc[i]; s += v * v; }
#pragma unroll
        for (int off = 32; off >= 1; off >>= 1) s += __shfl_xor(s, off);
        __shared__ float red[4];
        if (lane == 0) red[wv] = s;
        __syncthreads();
        if (t == 0) {
            wsf[WSQ_IDX + co] = red[0] + red[1] + red[2] + red[3];
            if (co == 0) wsf[SCALE_IDX] = powf(16.0f / log1pf(256.0f), alpha[0]);
        }
        if (co == 0 && t >= 8 && t < 16) wsf[ZERO_IDX + (t - 8)] = 0.f;
    }
}

// ---------------- per-patch squared norm: one wave per output pixel ----------------
__global__ void k_psq(const U16* __restrict__ xt, float* __restrict__ wsf) {
    int t = threadIdx.x, lane = t & 63, wv = t >> 6;
    int gm = blockIdx.x * 4 + wv;                  // < 25088 exactly
    int ow = gm % 28, tt = gm / 28;
    int oh = tt % 28, n = tt / 28;
    const U16* xb = xt + (size_t)n * 56 * 56 * 128;
    float s = 0.f;
#pragma unroll
    for (int kh = 0; kh < 3; ++kh) {
        int ih = oh * 2 - 1 + kh;
        if ((unsigned)ih >= 56) continue;
#pragma unroll
        for (int kw = 0; kw < 3; ++kw) {
            int iw = ow * 2 - 1 + kw;
            if ((unsigned)iw >= 56) continue;
            unsigned int v = *(const unsigned int*)&xb[(size_t)((ih * 56 + iw) << 7) + lane * 2];
            float f0 = b2f((U16)(v & 0xffff)), f1 = b2f((U16)(v >> 16));
            s += f0 * f0 + f1 * f1;
        }
    }
#pragma unroll
    for (int off = 32; off >= 1; off >>= 1) s += __shfl_xor(s, off);
    if (lane == 0) wsf[PSQ_IDX + gm] = s;
}

// ---------------- MFMA implicit-GEMM, BM=128 BN=128 BK=128, single-buffered ----------------
// 64 KB LDS -> 2 blocks/CU. 4 waves, each owns 64x64 (4x4 frags): 8 ds_reads feed 16 MFMAs.
// 9 K-steps per dispatch (halved). ALL stores coalesced [m][co] -- no NCHW scatter here.
// MODE 0: yat dot conv -> ybuf bf16[m][co]; fused 1x1 shortcut -> pout bf16[m][co]
// MODE 3: lin 3x3 s1 p1 over ybuf, split-K=2 (bid>=392 -> K-half 1) -> pout bf16[2][m][co]
template<int KTOT, int MODE>
__launch_bounds__(256, 2)
__global__ void k_gemm(const U16* __restrict__ Asrc, const U16* __restrict__ Bp,
                       const U16* __restrict__ B2p,
                       const float* __restrict__ wsf, U16* __restrict__ ybuf,
                       U16* __restrict__ pout) {
    __shared__ U16 Ab[128 * 128];                  // 32 KB
    __shared__ U16 Bb[128 * 128];                  // 32 KB  (total exactly 64 KB)

    int t = threadIdx.x, lane = t & 63, wv = t >> 6;
    int wr = wv >> 1, wc = wv & 1;                 // wave quadrant: rows wr*64, cols wc*64
    int bid = blockIdx.x;
    int s = 0, inner = bid;
    if (MODE == 3) { s = (bid >= 392) ? 1 : 0; inner = bid - 392 * s; }
    int logical = (inner & 7) * 49 + (inner >> 3); // XCD swizzle (392 = 8*49, bijective)
    int m0 = (logical >> 1) * 128;
    int co_base = (logical & 1) * 128;

    const U16* zptr = (const U16*)&wsf[ZERO_IDX];

    // Staging coords: thread t owns 16B unit (t&15) of rows/cols (t>>4)+16q, q=0..7.
    // LDS dest linear in t per q; source pre-swizzled: plog = (t&15) ^ ((t>>4)&15).
    int arow0 = t >> 4, apart = t & 15;
    int plog  = apart ^ (arow0 & 15);              // same for A rows and B cols (row&15 const over q)
    int an[8], aoh[8], aow[8];
#pragma unroll
    for (int q = 0; q < 8; ++q) {
        int am = m0 + arow0 + 16 * q;
        int tt = am / 28; aow[q] = am - tt * 28; an[q] = tt / 28; aoh[q] = tt - an[q] * 28;
    }

    f32x4 acc[4][4] = {};
    f32x4 acc2[4][4] = {};                         // identity (MODE0 only; DCE'd in MODE3)

    for (int kq = 0; kq < 9; ++kq) {
        int k0 = (MODE == 3 ? (s * 9 + kq) : kq) * 128;
        // ---- stage A [128 rows][128 k] ----
        if (MODE == 0) {
            int kh = kq / 3, kw = kq - 3 * kh;     // khkw == kq (128 ci per tap)
#pragma unroll
            for (int q = 0; q < 8; ++q) {
                int ih = aoh[q] * 2 - 1 + kh, iw = aow[q] * 2 - 1 + kw;
                bool v = ((unsigned)ih < 56) & ((unsigned)iw < 56);
                const U16* sp = v ? Asrc + ((size_t)((an[q] * 56 + ih) * 56 + iw) << 7) + plog * 8 : zptr;
                gl_lds16(sp, &Ab[(size_t)(q * 256 + t) * 8]);
            }
        } else {
            int khkw = k0 >> 8, cy0 = k0 & 255;
            int kh = khkw / 3, kw = khkw - 3 * kh;
#pragma unroll
            for (int q = 0; q < 8; ++q) {
                int ih = aoh[q] - 1 + kh, iw = aow[q] - 1 + kw;
                bool v = ((unsigned)ih < 28) & ((unsigned)iw < 28);
                const U16* sp = v ? Asrc + ((size_t)((an[q] * 28 + ih) * 28 + iw) << 8) + cy0 + plog * 8 : zptr;
                gl_lds16(sp, &Ab[(size_t)(q * 256 + t) * 8]);
            }
        }
        // ---- stage B [128 cols][128 k] ----
#pragma unroll
        for (int q = 0; q < 8; ++q) {
            const U16* sp = Bp + (size_t)(co_base + arow0 + 16 * q) * KTOT + k0 + plog * 8;
            gl_lds16(sp, &Bb[(size_t)(q * 256 + t) * 8]);
        }
        __syncthreads();
        // ---- MFMA: 4 kk-steps of K=32, 16 MFMA each ----
#pragma unroll
        for (int kk = 0; kk < 4; ++kk) {
            bf16x8 au[4], bu[4];
#pragma unroll
            for (int i = 0; i < 4; ++i) {
                int row = wr * 64 + i * 16 + (lane & 15);
                int pp = (kk * 4 + (lane >> 4)) ^ (row & 15);
                au[i] = *(const bf16x8*)&Ab[(row * 16 + pp) * 8];
            }
#pragma unroll
            for (int j = 0; j < 4; ++j) {
                int col = wc * 64 + j * 16 + (lane & 15);
                int pp = (kk * 4 + (lane >> 4)) ^ (col & 15);
                bu[j] = *(const bf16x8*)&Bb[(col * 16 + pp) * 8];
            }
#pragma unroll
            for (int i = 0; i < 4; ++i)
#pragma unroll
                for (int j = 0; j < 4; ++j)
                    acc[i][j] = __builtin_amdgcn_mfma_f32_16x16x32_bf16(au[i], bu[j], acc[i][j], 0, 0, 0);
            if (MODE == 0 && kq == 4) {            // center tap: fused 1x1 shortcut (B2 L2-hot)
#pragma unroll
                for (int j = 0; j < 4; ++j) {
                    int col = wc * 64 + j * 16 + (lane & 15);
                    int qp = kk * 4 + (lane >> 4);
                    bf16x8 b2v = *(const bf16x8*)&B2p[(size_t)(co_base + col) * 128 + qp * 8];
#pragma unroll
                    for (int i = 0; i < 4; ++i)
                        acc2[i][j] = __builtin_amdgcn_mfma_f32_16x16x32_bf16(au[i], b2v, acc2[i][j], 0, 0, 0);
                }
            }
        }
        __syncthreads();
    }

    // ---- epilogue: ALL stores coalesced [m][co] ----
    float scale = (MODE == 0) ? wsf[SCALE_IDX] : 0.f;
#pragma unroll
    for (int i = 0; i < 4; ++i)
#pragma unroll
        for (int j = 0; j < 4; ++j)
#pragma unroll
            for (int r = 0; r < 4; ++r) {
                int row = wr * 64 + i * 16 + ((lane >> 4) << 2) + r;
                int coll = wc * 64 + j * 16 + (lane & 15);
                int m = m0 + row;
                int co = co_base + coll;
                size_t oidx = (size_t)m * 256 + co;
                if (MODE == 0) {
                    float dot = acc[i][j][r];
                    float psq = wsf[PSQ_IDX + m];
                    float wsq = wsf[WSQ_IDX + co];
                    float dist = psq + wsq - 2.0f * dot + EPS_;
                    float y = dot * dot / dist * scale;
                    ybuf[oidx] = f2bf(y);
                    pout[oidx] = f2bf(acc2[i][j][r]);          // identity partial
                } else {
                    pout[(size_t)s * OUTSZ + oidx] = f2bf(acc[i][j][r]);
                }
            }
}

// ---------------- final reduce + transpose: out = pid + p0 + p1 (NCHW, coalesced) ----------
// block = (n, cog of 16 co); LDS [784 m][17] f32 transpose tile (conflict-free, 53.3 KB)
__global__ void k_red(const U16* __restrict__ pid, const U16* __restrict__ p01,
                      float* __restrict__ out) {
    __shared__ float tile[784 * 17];
    int t = threadIdx.x;
    int n = blockIdx.x >> 4, cog = blockIdx.x & 15;
    size_t base = (size_t)n * 784 * 256 + cog * 16;

    auto doRow = [&](int m) {
        size_t a = base + (size_t)m * 256;
        uint4 i0 = *(const uint4*)(pid + a);
        uint4 i1 = *(const uint4*)(pid + a + 8);
        uint4 a0 = *(const uint4*)(p01 + a);
        uint4 a1 = *(const uint4*)(p01 + a + 8);
        uint4 b0 = *(const uint4*)(p01 + (size_t)OUTSZ + a);
        uint4 b1 = *(const uint4*)(p01 + (size_t)OUTSZ + a + 8);
        const unsigned* iw_ = (const unsigned*)&i0;   // i0,i1 contiguous? no -- handle separately
        const unsigned* iw2 = (const unsigned*)&i1;
        const unsigned* aw  = (const unsigned*)&a0;
        const unsigned* aw2 = (const unsigned*)&a1;
        const unsigned* bw  = (const unsigned*)&b0;
        const unsigned* bw2 = (const unsigned*)&b1;
        float* row = &tile[m * 17];
#pragma unroll
        for (int w = 0; w < 4; ++w) {
            row[2 * w]     = b2f((U16)(iw_[w] & 0xffff)) + b2f((U16)(aw[w] & 0xffff)) + b2f((U16)(bw[w] & 0xffff));
            row[2 * w + 1] = b2f((U16)(iw_[w] >> 16))    + b2f((U16)(aw[w] >> 16))    + b2f((U16)(bw[w] >> 16));
            row[8 + 2 * w]     = b2f((U16)(iw2[w] & 0xffff)) + b2f((U16)(aw2[w] & 0xffff)) + b2f((U16)(bw2[w] & 0xffff));
            row[8 + 2 * w + 1] = b2f((U16)(iw2[w] >> 16))    + b2f((U16)(aw2[w] >> 16))    + b2f((U16)(bw2[w] >> 16));
        }
    };
    doRow(t);
    doRow(t + 256);
    doRow(t + 512);
    if (t < 16) doRow(t + 768);
    __syncthreads();

    int co = t >> 4, ml = t & 15;
    float* obase = out + ((size_t)(n * 256 + cog * 16 + co)) * 784;
#pragma unroll
    for (int j = 0; j < 49; ++j) {
        int m = ml + 16 * j;
        obase[m] = tile[m * 17 + co];
    }
}

extern "C" void kernel_launch(void* const* d_in, const int* in_sizes, int n_in,
                              void* d_out, int out_size, void* d_ws, size_t ws_size,
                              hipStream_t stream) {
    const float* x       = (const float*)d_in[0];
    const float* w_yat   = (const float*)d_in[1];
    const float* alpha   = (const float*)d_in[2];
    const float* w_lin   = (const float*)d_in[3];
    const float* w_short = (const float*)d_in[4];
    float* out = (float*)d_out;
    float* wsf = (float*)d_ws;

    U16* xt  = (U16*)((char*)d_ws + U16_BYTE_OFF);
    U16* yb  = xt + (size_t)N_ * H_ * W_ * CIN;       // 12,845,056 U16
    U16* B1  = yb + (size_t)OUTSZ;                    // +6,422,528
    U16* B2  = B1 + 1152 * COUT;                      // +294,912
    U16* B3  = B2 + CIN * COUT;                       // +32,768
    U16* pid = B3 + 2304 * COUT;                      // +589,824 -> identity partial (6,422,528)
    // lin split-K partials p0,p1 alias xt (dead after gemm0): 2 x OUTSZ U16 exactly

    k_prep<<<10112, 256, 0, stream>>>(x, w_yat, w_lin, w_short, alpha, xt, B1, B3, B2, wsf);
    k_psq <<<6272,  256, 0, stream>>>(xt, wsf);

    k_gemm<1152, 0><<<392, 256, 0, stream>>>(xt, B1, B2, wsf, yb, pid);
    k_gemm<2304, 3><<<784, 256, 0, stream>>>(yb, B3, nullptr, wsf, nullptr, xt);
    k_red <<<512, 256, 0, stream>>>(pid, xt, out);
}

// Round 11
// 138.802 us; speedup vs baseline: 1.4228x; 1.0453x over previous
//
#include <hip/hip_runtime.h>
#include <math.h>

#define N_    32
#define CIN   128
#define H_    56
#define W_    56
#define COUT  256
#define OH    28
#define OW    28
#define M_    (N_ * OH * OW)      // 25088
#define OUTSZ (M_ * COUT)         // 6,422,528
#define EPS_  0.007f

typedef unsigned short U16;
typedef float f32x4  __attribute__((ext_vector_type(4)));
typedef short bf16x8 __attribute__((ext_vector_type(8)));

// ws float-region layout
#define SCALE_IDX 0
#define ZERO_IDX  8             // wsf[8..15]: 32B zero page for OOB global_load_lds
#define WSQ_IDX   16            // 256 floats
#define U16_BYTE_OFF 102400     // = 25600 floats, 256B aligned

__device__ __forceinline__ U16 f2bf(float f) {
    unsigned int u = __builtin_bit_cast(unsigned int, f);
    u = (u + 0x7fffu + ((u >> 16) & 1u)) >> 16;   // RNE
    return (U16)u;
}
__device__ __forceinline__ float b2f(U16 h) {
    unsigned int u = ((unsigned int)h) << 16;
    return __builtin_bit_cast(float, u);
}

__device__ __forceinline__ void gl_lds16(const U16* g, U16* l) {
    __builtin_amdgcn_global_load_lds((const __attribute__((address_space(1))) void*)g,
                                     (__attribute__((address_space(3))) void*)l, 16, 0, 0);
}

// ---------------- fused prep: x transpose + weight reorder + wsq/scale/zero ----------------
__global__ void k_prep(const float* __restrict__ x,
                       const float* __restrict__ w_yat,
                       const float* __restrict__ w_lin,
                       const float* __restrict__ w_short,
                       const float* __restrict__ alpha,
                       U16* __restrict__ xt, U16* __restrict__ B1,
                       U16* __restrict__ B3, U16* __restrict__ B2,
                       float* __restrict__ wsf) {
    int b = blockIdx.x, t = threadIdx.x;
    if (b < 6272) {
        int idx = b * 256 + t;                     // 1,605,632 exactly
        int ci8 = idx & 15;
        int px  = idx >> 4;                        // n*3136 + hw
        int n   = px / 3136;
        int hw  = px - n * 3136;
        const float* src = x + ((size_t)n * 128 + ci8 * 8) * 3136 + hw;
        unsigned int o[4];
#pragma unroll
        for (int j = 0; j < 4; ++j) {
            float a = src[(size_t)(2 * j)     * 3136];
            float c = src[(size_t)(2 * j + 1) * 3136];
            o[j] = (unsigned)f2bf(a) | ((unsigned)f2bf(c) << 16);
        }
        *(uint4*)&xt[(size_t)px * 128 + ci8 * 8] = *(const uint4*)o;
    } else if (b < 9856) {
        int idx = (b - 6272) * 256 + t;            // 917,504 exactly
        if (idx < 294912) {
            int co = idx / 1152, k = idx % 1152;
            int khkw = k >> 7, ci = k & 127;
            B1[idx] = f2bf(w_yat[(co * 128 + ci) * 9 + khkw]);
        } else if (idx < 294912 + 589824) {
            int i2 = idx - 294912;
            int co = i2 / 2304, k = i2 % 2304;
            int khkw = k >> 8, cy = k & 255;
            B3[i2] = f2bf(w_lin[(co * 256 + cy) * 9 + khkw]);
        } else {
            int i3 = idx - (294912 + 589824);      // < 32768
            B2[i3] = f2bf(w_short[i3]);
        }
    } else {
        int co = b - 9856, lane = t & 63, wv = t >> 6;
        const float* wc = w_yat + (size_t)co * 1152;
        float s = 0.f;
        for (int i = t; i < 1152; i += 256) { float v = wc[i]; s += v * v; }
#pragma unroll
        for (int off = 32; off >= 1; off >>= 1) s += __shfl_xor(s, off);
        __shared__ float red[4];
        if (lane == 0) red[wv] = s;
        __syncthreads();
        if (t == 0) {
            wsf[WSQ_IDX + co] = red[0] + red[1] + red[2] + red[3];
            if (co == 0) wsf[SCALE_IDX] = powf(16.0f / log1pf(256.0f), alpha[0]);
        }
        if (co == 0 && t >= 8 && t < 16) wsf[ZERO_IDX + (t - 8)] = 0.f;
    }
}

// ---------------- k_yat: yat dot conv + fused psq + fused 1x1 shortcut ----------------
// BM=BN=128, BK=128, 9 K-steps (one per tap). psq computed from the SAME zero-masked
// A fragments the MFMA loads (wc==0 waves), so k_psq dispatch is eliminated.
__launch_bounds__(256, 2)
__global__ void k_yat(const U16* __restrict__ xt, const U16* __restrict__ B1,
                      const U16* __restrict__ B2p, const float* __restrict__ wsf,
                      U16* __restrict__ ybuf, U16* __restrict__ pid) {
    __shared__ U16 Ab[128 * 128];                  // 32 KB
    __shared__ U16 Bb[128 * 128];                  // 32 KB
    __shared__ float psq_s[128];

    int t = threadIdx.x, lane = t & 63, wv = t >> 6;
    int wr = wv >> 1, wc = wv & 1;
    int bid = blockIdx.x;                          // 392 = 8*49
    int logical = (bid & 7) * 49 + (bid >> 3);
    int m0 = (logical >> 1) * 128;
    int co_base = (logical & 1) * 128;

    const U16* zptr = (const U16*)&wsf[ZERO_IDX];

    int arow0 = t >> 4, apart = t & 15;
    int plog  = apart ^ (arow0 & 15);
    int an[8], aoh[8], aow[8];
#pragma unroll
    for (int q = 0; q < 8; ++q) {
        int am = m0 + arow0 + 16 * q;
        int tt = am / 28; aow[q] = am - tt * 28; an[q] = tt / 28; aoh[q] = tt - an[q] * 28;
    }

    f32x4 acc[4][4] = {};
    f32x4 acc2[4][4] = {};
    float p[4] = {0.f, 0.f, 0.f, 0.f};             // psq partials (wc==0 waves)

    for (int kq = 0; kq < 9; ++kq) {
        int kh = kq / 3, kw = kq - 3 * kh;
        // ---- stage A [128 m][128 ci] for tap kq ----
#pragma unroll
        for (int q = 0; q < 8; ++q) {
            int ih = aoh[q] * 2 - 1 + kh, iw = aow[q] * 2 - 1 + kw;
            bool v = ((unsigned)ih < 56) & ((unsigned)iw < 56);
            const U16* sp = v ? xt + ((size_t)((an[q] * 56 + ih) * 56 + iw) << 7) + plog * 8 : zptr;
            gl_lds16(sp, &Ab[(size_t)(q * 256 + t) * 8]);
        }
        // ---- stage B [128 co][128 ci] ----
#pragma unroll
        for (int q = 0; q < 8; ++q) {
            const U16* sp = B1 + (size_t)(co_base + arow0 + 16 * q) * 1152 + kq * 128 + plog * 8;
            gl_lds16(sp, &Bb[(size_t)(q * 256 + t) * 8]);
        }
        __syncthreads();
        // ---- MFMA + psq ----
#pragma unroll
        for (int kk = 0; kk < 4; ++kk) {
            bf16x8 au[4], bu[4];
#pragma unroll
            for (int i = 0; i < 4; ++i) {
                int row = wr * 64 + i * 16 + (lane & 15);
                int pp = (kk * 4 + (lane >> 4)) ^ (row & 15);
                au[i] = *(const bf16x8*)&Ab[(row * 16 + pp) * 8];
            }
#pragma unroll
            for (int j = 0; j < 4; ++j) {
                int col = wc * 64 + j * 16 + (lane & 15);
                int pp = (kk * 4 + (lane >> 4)) ^ (col & 15);
                bu[j] = *(const bf16x8*)&Bb[(col * 16 + pp) * 8];
            }
            if (wc == 0) {                         // psq: sum of squares of masked A
#pragma unroll
                for (int i = 0; i < 4; ++i)
#pragma unroll
                    for (int e = 0; e < 8; ++e) {
                        float v = b2f((U16)au[i][e]);
                        p[i] += v * v;
                    }
            }
#pragma unroll
            for (int i = 0; i < 4; ++i)
#pragma unroll
                for (int j = 0; j < 4; ++j)
                    acc[i][j] = __builtin_amdgcn_mfma_f32_16x16x32_bf16(au[i], bu[j], acc[i][j], 0, 0, 0);
            if (kq == 4) {                         // center tap: fused 1x1 shortcut
#pragma unroll
                for (int j = 0; j < 4; ++j) {
                    int col = wc * 64 + j * 16 + (lane & 15);
                    int qp = kk * 4 + (lane >> 4);
                    bf16x8 b2v = *(const bf16x8*)&B2p[(size_t)(co_base + col) * 128 + qp * 8];
#pragma unroll
                    for (int i = 0; i < 4; ++i)
                        acc2[i][j] = __builtin_amdgcn_mfma_f32_16x16x32_bf16(au[i], b2v, acc2[i][j], 0, 0, 0);
                }
            }
        }
        __syncthreads();
    }

    // ---- psq reduce across the 4 k-part lanes (lanes r, r+16, r+32, r+48) ----
    if (wc == 0) {
#pragma unroll
        for (int i = 0; i < 4; ++i) {
            p[i] += __shfl_xor(p[i], 16);
            p[i] += __shfl_xor(p[i], 32);
            if (lane < 16) psq_s[wr * 64 + i * 16 + lane] = p[i];
        }
    }
    __syncthreads();

    // ---- epilogue: coalesced [m][co] stores ----
    float scale = wsf[SCALE_IDX];
#pragma unroll
    for (int i = 0; i < 4; ++i)
#pragma unroll
        for (int j = 0; j < 4; ++j)
#pragma unroll
            for (int r = 0; r < 4; ++r) {
                int row = wr * 64 + i * 16 + ((lane >> 4) << 2) + r;
                int coll = wc * 64 + j * 16 + (lane & 15);
                int m = m0 + row;
                int co = co_base + coll;
                size_t oidx = (size_t)m * 256 + co;
                float dot = acc[i][j][r];
                float dist = psq_s[row] + wsf[WSQ_IDX + co] - 2.0f * dot + EPS_;
                float y = dot * dot / dist * scale;
                ybuf[oidx] = f2bf(y);
                pid[oidx]  = f2bf(acc2[i][j][r]);
            }
}

// ---------------- k_lin: 3x3 s1 p1 conv over ybuf with A-HALO LDS reuse ----------------
// Per block: stage ybuf rows [m0-32, m0+160) x 128-ci-half ONCE (48 KB), then 9 taps
// each staging only the 32 KB B-tile. Split = ci-half (2 partials). Tap validity
// masked per-lane on the A fragment.
__launch_bounds__(256, 2)
__global__ void k_lin(const U16* __restrict__ yb, const U16* __restrict__ B3,
                      U16* __restrict__ pout) {
    __shared__ U16 Ah[192 * 128];                  // 48 KB halo
    __shared__ U16 Bt[128 * 128];                  // 32 KB

    int t = threadIdx.x, lane = t & 63, wv = t >> 6;
    int wr = wv >> 1, wc = wv & 1;
    int bid = blockIdx.x;                          // 784 = 2 cihalf * 2 co * 196 m
    int s = (bid >= 392) ? 1 : 0;
    int inner = bid - 392 * s;
    int co_sel = (inner >= 196) ? 1 : 0;
    int mt = inner - 196 * co_sel;
    // m204 bijective XCD swizzle over 196 (q=24, r=4)
    int xcd = mt & 7, pos = mt >> 3;
    int swz = (xcd < 4 ? xcd * 25 : 100 + (xcd - 4) * 24) + pos;
    int m0 = swz * 128;
    int co_base = co_sel * 128;
    int kci = s * 128;

    // ---- stage A halo: 192 rows x 128 ci-half (12 rounds) ----
#pragma unroll
    for (int q = 0; q < 12; ++q) {
        int u = q * 256 + t;
        int row = u >> 4, part = u & 15;
        int plog = part ^ (row & 15);
        int mm = m0 - 32 + row;
        mm = mm < 0 ? 0 : (mm >= M_ ? M_ - 1 : mm);
        gl_lds16(yb + (size_t)mm * 256 + kci + plog * 8, &Ah[(size_t)u * 8]);
    }

    // B staging coords
    int brow = t >> 4, bpart = t & 15;
    int bplog = bpart ^ (brow & 15);

    // per-i row coords + validity precompute
    int mrow[4], owv[4], ohv[4];
#pragma unroll
    for (int i = 0; i < 4; ++i) {
        mrow[i] = wr * 64 + i * 16 + (lane & 15);
        int m = m0 + mrow[i];
        int tt = m / 28; owv[i] = m - tt * 28; ohv[i] = tt % 28;
    }

    f32x4 acc[4][4] = {};

    for (int tap = 0; tap < 9; ++tap) {
        int kh = tap / 3, kw = tap - 3 * kh;
        int dlt = (kh - 1) * 28 + (kw - 1);
        // ---- stage B [128 co][128 k] for this tap ----
#pragma unroll
        for (int q = 0; q < 8; ++q) {
            const U16* sp = B3 + (size_t)(co_base + brow + 16 * q) * 2304 + tap * 256 + kci + bplog * 8;
            gl_lds16(sp, &Bt[(size_t)(q * 256 + t) * 8]);
        }
        __syncthreads();                           // drains A-halo (tap 0) + B

        bool val[4];
#pragma unroll
        for (int i = 0; i < 4; ++i)
            val[i] = ((unsigned)(owv[i] + kw - 1) < 28u) & ((unsigned)(ohv[i] + kh - 1) < 28u);

#pragma unroll
        for (int kk = 0; kk < 4; ++kk) {
            bf16x8 au[4], bu[4];
#pragma unroll
            for (int i = 0; i < 4; ++i) {
                int ra = mrow[i] + 32 + dlt;       // halo row in [3, 189)
                int pp = (kk * 4 + (lane >> 4)) ^ (ra & 15);
                bf16x8 av = *(const bf16x8*)&Ah[(ra * 16 + pp) * 8];
                bf16x8 z = {};
                au[i] = val[i] ? av : z;
            }
#pragma unroll
            for (int j = 0; j < 4; ++j) {
                int col = wc * 64 + j * 16 + (lane & 15);
                int pp = (kk * 4 + (lane >> 4)) ^ (col & 15);
                bu[j] = *(const bf16x8*)&Bt[(col * 16 + pp) * 8];
            }
#pragma unroll
            for (int i = 0; i < 4; ++i)
#pragma unroll
                for (int j = 0; j < 4; ++j)
                    acc[i][j] = __builtin_amdgcn_mfma_f32_16x16x32_bf16(au[i], bu[j], acc[i][j], 0, 0, 0);
        }
        __syncthreads();                           // Bt reuse next tap (Ah untouched)
    }

    // ---- epilogue: coalesced bf16 partials [s][m][co] ----
#pragma unroll
    for (int i = 0; i < 4; ++i)
#pragma unroll
        for (int j = 0; j < 4; ++j)
#pragma unroll
            for (int r = 0; r < 4; ++r) {
                int row = wr * 64 + i * 16 + ((lane >> 4) << 2) + r;
                int coll = wc * 64 + j * 16 + (lane & 15);
                size_t oidx = (size_t)(m0 + row) * 256 + co_base + coll;
                pout[(size_t)s * OUTSZ + oidx] = f2bf(acc[i][j][r]);
            }
}

// ---------------- final reduce + transpose: out = pid + p0 + p1 (NCHW, coalesced) ----------
__global__ void k_red(const U16* __restrict__ pid, const U16* __restrict__ p01,
                      float* __restrict__ out) {
    __shared__ float tile[784 * 17];
    int t = threadIdx.x;
    int n = blockIdx.x >> 4, cog = blockIdx.x & 15;
    size_t base = (size_t)n * 784 * 256 + cog * 16;

    auto doRow = [&](int m) {
        size_t a = base + (size_t)m * 256;
        uint4 i0 = *(const uint4*)(pid + a);
        uint4 i1 = *(const uint4*)(pid + a + 8);
        uint4 a0 = *(const uint4*)(p01 + a);
        uint4 a1 = *(const uint4*)(p01 + a + 8);
        uint4 b0 = *(const uint4*)(p01 + (size_t)OUTSZ + a);
        uint4 b1 = *(const uint4*)(p01 + (size_t)OUTSZ + a + 8);
        const unsigned* iw_ = (const unsigned*)&i0;
        const unsigned* iw2 = (const unsigned*)&i1;
        const unsigned* aw  = (const unsigned*)&a0;
        const unsigned* aw2 = (const unsigned*)&a1;
        const unsigned* bw  = (const unsigned*)&b0;
        const unsigned* bw2 = (const unsigned*)&b1;
        float* row = &tile[m * 17];
#pragma unroll
        for (int w = 0; w < 4; ++w) {
            row[2 * w]     = b2f((U16)(iw_[w] & 0xffff)) + b2f((U16)(aw[w] & 0xffff)) + b2f((U16)(bw[w] & 0xffff));
            row[2 * w + 1] = b2f((U16)(iw_[w] >> 16))    + b2f((U16)(aw[w] >> 16))    + b2f((U16)(bw[w] >> 16));
            row[8 + 2 * w]     = b2f((U16)(iw2[w] & 0xffff)) + b2f((U16)(aw2[w] & 0xffff)) + b2f((U16)(bw2[w] & 0xffff));
            row[8 + 2 * w + 1] = b2f((U16)(iw2[w] >> 16))    + b2f((U16)(aw2[w] >> 16))    + b2f((U16)(bw2[w] >> 16));
        }
    };
    doRow(t);
    doRow(t + 256);
    doRow(t + 512);
    if (t < 16) doRow(t + 768);
    __syncthreads();

    int co = t >> 4, ml = t & 15;
    float* obase = out + ((size_t)(n * 256 + cog * 16 + co)) * 784;
#pragma unroll
    for (int j = 0; j < 49; ++j) {
        int m = ml + 16 * j;
        obase[m] = tile[m * 17 + co];
    }
}

extern "C" void kernel_launch(void* const* d_in, const int* in_sizes, int n_in,
                              void* d_out, int out_size, void* d_ws, size_t ws_size,
                              hipStream_t stream) {
    const float* x       = (const float*)d_in[0];
    const float* w_yat   = (const float*)d_in[1];
    const float* alpha   = (const float*)d_in[2];
    const float* w_lin   = (const float*)d_in[3];
    const float* w_short = (const float*)d_in[4];
    float* out = (float*)d_out;
    float* wsf = (float*)d_ws;

    U16* xt  = (U16*)((char*)d_ws + U16_BYTE_OFF);
    U16* yb  = xt + (size_t)N_ * H_ * W_ * CIN;       // 12,845,056 U16
    U16* B1  = yb + (size_t)OUTSZ;                    // +6,422,528
    U16* B2  = B1 + 1152 * COUT;                      // +294,912
    U16* B3  = B2 + CIN * COUT;                       // +32,768
    U16* pid = B3 + 2304 * COUT;                      // +589,824 -> identity partial
    // lin partials p0,p1 alias xt (dead after k_yat): 2 x OUTSZ U16 exactly

    k_prep<<<10112, 256, 0, stream>>>(x, w_yat, w_lin, w_short, alpha, xt, B1, B3, B2, wsf);

    k_yat<<<392, 256, 0, stream>>>(xt, B1, B2, wsf, yb, pid);
    k_lin<<<784, 256, 0, stream>>>(yb, B3, xt);
    k_red<<<512, 256, 0, stream>>>(pid, xt, out);
}